// Round 15
// baseline (728.380 us; speedup 1.0000x reference)
//
#include <hip/hip_runtime.h>

// Problem constants
#define V_N 256
#define T_N 256
#define K_N 36
#define L_N 32
#define D_N 1024
#define MROWS (V_N * K_N)         // 9216
#define NROWS (T_N * L_N)         // 8192
#define BM 256
#define BN 256
#define TB 128                    // K-tile BYTES per row (128 fp8 = K=128)
#define KSTEPS (D_N / TB)         // 8
#define NBM (MROWS / BM)          // 36
#define NBN (NROWS / BN)          // 32
#define NWG (NBM * NBN)           // 1152

typedef __attribute__((ext_vector_type(8))) int i32x8;
typedef __attribute__((ext_vector_type(4))) float f32x4;

#define BAR __builtin_amdgcn_s_barrier()
#define LGK0 asm volatile("s_waitcnt lgkmcnt(0)" ::: "memory")
#define SCL1 0x7F7F7F7F           // E8M0 = 127 -> 2^0 in every byte (layout-proof)

__device__ __forceinline__ unsigned char f2e4m3(float x) {
  union { float f; unsigned int u; } c; c.f = x;
  unsigned int s = (c.u >> 24) & 0x80u;
  float ax = fabsf(x);
  if (ax < 0.015625f) return (unsigned char)s;            // flush tiny (<2^-6)
  if (ax > 448.f)     return (unsigned char)(s | 0x7Eu);  // saturate
  unsigned int u = c.u & 0x7FFFFFFFu;
  unsigned int r = u + 0x7FFFFu + ((u >> 20) & 1u);       // RNE into 3-bit mantissa
  unsigned int e8 = (r >> 23) - 120u;                     // bias 127->7
  unsigned int m = (r >> 20) & 7u;
  if (e8 >= 15u && (e8 > 15u || m > 6u)) return (unsigned char)(s | 0x7Eu);
  return (unsigned char)(s | (e8 << 3) | m);
}

// ---------------- conversion: fp32 -> e4m3 flat (row-major, 1B/elem) --------
__global__ void cvt8(const float* __restrict__ imgs, const float* __restrict__ caps,
                     unsigned char* __restrict__ a8, unsigned char* __restrict__ b8) {
  const int AG = MROWS * (D_N / 8);   // 8-elem groups in A
  const int total = AG + NROWS * (D_N / 8);
  for (int g = blockIdx.x * blockDim.x + threadIdx.x; g < total;
       g += gridDim.x * blockDim.x) {
    const float4* src;
    unsigned char* dst;
    if (g < AG) { src = reinterpret_cast<const float4*>(imgs) + (size_t)g * 2; dst = a8 + (size_t)g * 8; }
    else { int q = g - AG; src = reinterpret_cast<const float4*>(caps) + (size_t)q * 2; dst = b8 + (size_t)q * 8; }
    float4 f0 = src[0], f1 = src[1];
    union { unsigned char b[8]; uint2 v; } pk;
    pk.b[0] = f2e4m3(f0.x); pk.b[1] = f2e4m3(f0.y);
    pk.b[2] = f2e4m3(f0.z); pk.b[3] = f2e4m3(f0.w);
    pk.b[4] = f2e4m3(f1.x); pk.b[5] = f2e4m3(f1.y);
    pk.b[6] = f2e4m3(f1.z); pk.b[7] = f2e4m3(f1.w);
    *reinterpret_cast<uint2*>(dst) = pk.v;
  }
}

// ---------------- 256x256 fp8-MX GEMM + square + block-sum ------------------
// R14 = R13's verified skeleton, byte-identical LDS/stage/gate structure,
// ported to fp8 e4m3 with K=128 MFMA (mfma_scale_f32_16x16x128_f8f6f4,
// uniform scale 2^0). Rows are 128 B in both versions; stage units 16 KB,
// swizzle, barriers, vmcnt gates (10/8 steady, 8/2 then 0/0 tail) unchanged.
// KSTEPS halves 16->8: half the phases, half the barriers, half the staging.
// A/B operand k-mapping: lane l, byte j -> k = (l>>4)*32 + j (lane-group-
// contiguous rule, verified for 16x16x32 bf16 and 32x32x16 bf16).
// C/D layout is shape-determined (16x16): col=lane&15, row=(lane>>4)*4+reg.
__global__ __launch_bounds__(512, 2) void gemm2(
    const unsigned char* __restrict__ a8, const unsigned char* __restrict__ b8,
    float* __restrict__ out) {
  __shared__ unsigned char lds[2 * 2 * BM * TB];   // 128 KiB

  int orig = (int)blockIdx.x;
  int xcd = orig & 7;
  int idx = orig >> 3;                 // 0..143
  const int bn = xcd * 4 + (idx & 3);  // 4-wide bn band per XCD (B L2-resident)
  const int bm = idx >> 2;             // slow sweep
  const int row0 = bm * BM;
  const int col0 = bn * BN;

  const int tid  = (int)threadIdx.x;
  const int lane = tid & 63;
  const int wid  = tid >> 6;
  const int wr   = wid >> 2;     // 0..1  -> 128-row A slab
  const int wc   = wid & 3;      // 0..3  -> 64-row B slab

  // stage one 16KB unit (2 gload_lds/thread). kinds:
  // 0=Am03 rows{0-63,128-191}, 1=Am47 rows{64-127,192-255},
  // 2=B1 rows{0-127}, 3=B2 rows{128-255}
  auto stage_unit = [&](int kt, int kind) {
    const int rb0 = (kind == 0) ? 0 : (kind == 1) ? 64 : (kind == 2) ? 0 : 128;
    const int rb1 = (kind == 0) ? 128 : (kind == 1) ? 192 : (kind == 2) ? 64 : 192;
    unsigned char* base = lds + (kt & 1) * (2 * BM * TB) + ((kind >= 2) ? BM * TB : 0);
    const unsigned char* g = (kind >= 2) ? b8 : a8;
    const int g0 = (kind >= 2) ? col0 : row0;
#pragma unroll
    for (int j = 0; j < 2; ++j) {
      int r = (j ? rb1 : rb0) + (tid >> 3);
      int sw = ((tid & 7) << 4) ^ ((r & 7) << 4);
      const unsigned char* src = g + (size_t)(g0 + r) * D_N + kt * TB + sw;
      __builtin_amdgcn_global_load_lds(
          (const __attribute__((address_space(1))) void*)src,
          (__attribute__((address_space(3))) void*)(base + r * TB + (tid & 7) * 16),
          16, 0, 0);
    }
  };

  // fragment read: 32 B/lane as two swizzled 16B chunks
  auto rdA = [&](const unsigned char* bufA, int m, i32x8* dst) {
    int r = wr * 128 + m * 16 + (lane & 15);
    int cb = (lane >> 4) << 5;
    int sw0 = cb ^ ((r & 7) << 4);
    int sw1 = (cb + 16) ^ ((r & 7) << 4);
    union { int4 q[2]; i32x8 v; } u;
    u.q[0] = *reinterpret_cast<const int4*>(bufA + r * TB + sw0);
    u.q[1] = *reinterpret_cast<const int4*>(bufA + r * TB + sw1);
    *dst = u.v;
  };
  auto rdB = [&](const unsigned char* bufB, int n, i32x8* dst) {
    int r = wc * 64 + n * 16 + (lane & 15);
    int cb = (lane >> 4) << 5;
    int sw0 = cb ^ ((r & 7) << 4);
    int sw1 = (cb + 16) ^ ((r & 7) << 4);
    union { int4 q[2]; i32x8 v; } u;
    u.q[0] = *reinterpret_cast<const int4*>(bufB + r * TB + sw0);
    u.q[1] = *reinterpret_cast<const int4*>(bufB + r * TB + sw1);
    *dst = u.v;
  };

  f32x4 acc[8][4];
#pragma unroll
  for (int m = 0; m < 8; ++m)
#pragma unroll
    for (int n = 0; n < 4; ++n) acc[m][n] = (f32x4){0.f, 0.f, 0.f, 0.f};

  // ---- prologue: t0 fully + t1's {Am03,B1,B2}; gate so t0 landed
  stage_unit(0, 0); stage_unit(0, 2); stage_unit(0, 3); stage_unit(0, 1);
  stage_unit(1, 0); stage_unit(1, 2); stage_unit(1, 3);
  asm volatile("s_waitcnt vmcnt(6)" ::: "memory");
  BAR;

  // ---- main loop (8 K-tiles of K=128)
  for (int t = 0; t < KSTEPS; ++t) {
    const unsigned char* bufA = lds + (t & 1) * (2 * BM * TB);
    const unsigned char* bufB = bufA + BM * TB;
    i32x8 aA[4], b01[2], b23[2];

    // ======== p0: reads A(m0-3)+B(n0-1); stage Am47(t+1); MFMA m03 x n01
#pragma unroll
    for (int m = 0; m < 4; ++m) rdA(bufA, m, &aA[m]);
#pragma unroll
    for (int n = 0; n < 2; ++n) rdB(bufB, n, &b01[n]);
    if (t <= KSTEPS - 2) stage_unit(t + 1, 1);
    BAR; LGK0;
    __builtin_amdgcn_s_setprio(1);
#pragma unroll
    for (int m = 0; m < 4; ++m)
#pragma unroll
      for (int n = 0; n < 2; ++n)
        acc[m][n] = __builtin_amdgcn_mfma_scale_f32_16x16x128_f8f6f4(
            aA[m], b01[n], acc[m][n], 0, 0, 0, SCL1, 0, SCL1);
    __builtin_amdgcn_s_setprio(0);
    BAR;

    // ======== p1: reads B(n2-3); stage Am03(t+2); MFMA m03 x n23; gate
#pragma unroll
    for (int n = 0; n < 2; ++n) rdB(bufB, 2 + n, &b23[n]);
    if (t <= KSTEPS - 3) stage_unit(t + 2, 0);
    BAR; LGK0;
    __builtin_amdgcn_s_setprio(1);
#pragma unroll
    for (int m = 0; m < 4; ++m)
#pragma unroll
      for (int n = 0; n < 2; ++n)
        acc[m][2 + n] = __builtin_amdgcn_mfma_scale_f32_16x16x128_f8f6f4(
            aA[m], b23[n], acc[m][2 + n], 0, 0, 0, SCL1, 0, SCL1);
    __builtin_amdgcn_s_setprio(0);
    if (t <= KSTEPS - 3)      { asm volatile("s_waitcnt vmcnt(10)" ::: "memory"); }
    else if (t == KSTEPS - 2) { asm volatile("s_waitcnt vmcnt(8)"  ::: "memory"); }
    else                      { asm volatile("s_waitcnt vmcnt(0)"  ::: "memory"); }
    BAR;

    // ======== p2: reads A(m4-7); stage B1(t+2); MFMA m47 x n01
#pragma unroll
    for (int m = 0; m < 4; ++m) rdA(bufA, 4 + m, &aA[m]);
    if (t <= KSTEPS - 3) stage_unit(t + 2, 2);
    BAR; LGK0;
    __builtin_amdgcn_s_setprio(1);
#pragma unroll
    for (int m = 0; m < 4; ++m)
#pragma unroll
      for (int n = 0; n < 2; ++n)
        acc[4 + m][n] = __builtin_amdgcn_mfma_scale_f32_16x16x128_f8f6f4(
            aA[m], b01[n], acc[4 + m][n], 0, 0, 0, SCL1, 0, SCL1);
    __builtin_amdgcn_s_setprio(0);
    BAR;

    // ======== p3: no reads; stage B2(t+2); MFMA m47 x n23; gate
    if (t <= KSTEPS - 3) stage_unit(t + 2, 3);
    BAR;
    __builtin_amdgcn_s_setprio(1);
#pragma unroll
    for (int m = 0; m < 4; ++m)
#pragma unroll
      for (int n = 0; n < 2; ++n)
        acc[4 + m][2 + n] = __builtin_amdgcn_mfma_scale_f32_16x16x128_f8f6f4(
            aA[m], b23[n], acc[4 + m][2 + n], 0, 0, 0, SCL1, 0, SCL1);
    __builtin_amdgcn_s_setprio(0);
    if (t <= KSTEPS - 3)      { asm volatile("s_waitcnt vmcnt(8)" ::: "memory"); }
    else if (t == KSTEPS - 2) { asm volatile("s_waitcnt vmcnt(2)" ::: "memory"); }
    else                      { asm volatile("s_waitcnt vmcnt(0)" ::: "memory"); }
    BAR;
  }

  // ---- epilogue: squared block-sums. C/D: col=lane&15, row=(lane>>4)*4+reg.
#pragma unroll
  for (int m = 0; m < 8; ++m) {
    int grow = row0 + wr * 128 + m * 16;
    int v0 = grow / K_N;
    int b = (v0 + 1) * K_N;
    int rb = grow + ((lane >> 4) << 2);
#pragma unroll
    for (int np = 0; np < 2; ++np) {
      float s0 = 0.f, s1 = 0.f;
#pragma unroll
      for (int nn = 0; nn < 2; ++nn) {
        f32x4 a4 = acc[m][np * 2 + nn];
#pragma unroll
        for (int rg = 0; rg < 4; ++rg) {
          float x = a4[rg];
          float x2 = x * x;
          if (rb + rg < b) s0 += x2; else s1 += x2;
        }
      }
#pragma unroll
      for (int off = 32; off > 0; off >>= 1) {
        s0 += __shfl_xor(s0, off, 64);
        s1 += __shfl_xor(s1, off, 64);
      }
      if (lane == 0) {
        int tcol = (col0 + wc * 64 + np * 32) >> 5;
        atomicAdd(out + v0 * T_N + tcol, s0);
        if (grow + 16 > b) atomicAdd(out + (v0 + 1) * T_N + tcol, s1);
      }
    }
  }
}

// ---------------- fallback (no workspace): bf16 reg-staged 128x128 ----------
typedef __attribute__((ext_vector_type(8))) short bf16x8;
__device__ __forceinline__ ushort f2bf(float x) {
  union { float f; unsigned int u; } c; c.f = x;
  unsigned int r = c.u + 0x7FFFu + ((c.u >> 16) & 1u);
  return (ushort)(r >> 16);
}
__global__ __launch_bounds__(256) void gemm_fb(
    const float* __restrict__ imgs, const float* __restrict__ caps,
    float* __restrict__ out) {
  __shared__ ushort lds[128 * 64 + 128 * 64];
  ushort* ldsA = lds;
  ushort* ldsB = lds + 128 * 64;
  const int NBMf = MROWS / 128, NBNf = NROWS / 128;
  int orig = (int)blockIdx.x;
  int xcd = orig & 7;
  int idx = orig >> 3;
  int bn = xcd * (NBNf / 8) + (idx % (NBNf / 8));
  int bm = idx / (NBNf / 8);
  const int row0 = bm * 128, col0 = bn * 128;
  const int tid = (int)threadIdx.x, lane = tid & 63, wid = tid >> 6;
  const int wr = wid >> 1, wc = wid & 1;
  f32x4 acc[4][4];
#pragma unroll
  for (int i = 0; i < 4; ++i)
#pragma unroll
    for (int j = 0; j < 4; ++j) acc[i][j] = (f32x4){0.f, 0.f, 0.f, 0.f};
  for (int kt = 0; kt < 16; ++kt) {
#pragma unroll
    for (int it = 0; it < 4; ++it) {
      int q = it * 256 + tid;
      int r = q >> 3;
      int sw = ((q & 7) << 4) ^ ((r & 7) << 4);
      const float4* src = reinterpret_cast<const float4*>(
          imgs + (size_t)(row0 + r) * D_N + kt * 64 + (sw >> 1));
      float4 f0 = src[0], f1 = src[1];
      union { ushort u[8]; int4 v4; } pk;
      pk.u[0] = f2bf(f0.x); pk.u[1] = f2bf(f0.y); pk.u[2] = f2bf(f0.z); pk.u[3] = f2bf(f0.w);
      pk.u[4] = f2bf(f1.x); pk.u[5] = f2bf(f1.y); pk.u[6] = f2bf(f1.z); pk.u[7] = f2bf(f1.w);
      *reinterpret_cast<int4*>(ldsA + q * 8) = pk.v4;
    }
#pragma unroll
    for (int it = 0; it < 4; ++it) {
      int q = it * 256 + tid;
      int r = q >> 3;
      int sw = ((q & 7) << 4) ^ ((r & 7) << 4);
      const float4* src = reinterpret_cast<const float4*>(
          caps + (size_t)(col0 + r) * D_N + kt * 64 + (sw >> 1));
      float4 f0 = src[0], f1 = src[1];
      union { ushort u[8]; int4 v4; } pk;
      pk.u[0] = f2bf(f0.x); pk.u[1] = f2bf(f0.y); pk.u[2] = f2bf(f0.z); pk.u[3] = f2bf(f0.w);
      pk.u[4] = f2bf(f1.x); pk.u[5] = f2bf(f1.y); pk.u[6] = f2bf(f1.z); pk.u[7] = f2bf(f1.w);
      *reinterpret_cast<int4*>(ldsB + q * 8) = pk.v4;
    }
    __syncthreads();
#pragma unroll
    for (int ks = 0; ks < 2; ++ks) {
      bf16x8 afr[4], bfr[4];
#pragma unroll
      for (int i = 0; i < 4; ++i) {
        int r = wr * 64 + i * 16 + (lane & 15);
        int sw = (ks * 64 + (((lane >> 4) << 4))) ^ ((r & 7) << 4);
        afr[i] = *reinterpret_cast<const bf16x8*>(ldsA + r * 64 + (sw >> 1));
      }
#pragma unroll
      for (int j = 0; j < 4; ++j) {
        int r = wc * 64 + j * 16 + (lane & 15);
        int sw = (ks * 64 + (((lane >> 4) << 4))) ^ ((r & 7) << 4);
        bfr[j] = *reinterpret_cast<const bf16x8*>(ldsB + r * 64 + (sw >> 1));
      }
#pragma unroll
      for (int i = 0; i < 4; ++i)
#pragma unroll
        for (int j = 0; j < 4; ++j)
          acc[i][j] = __builtin_amdgcn_mfma_f32_16x16x32_bf16(afr[i], bfr[j], acc[i][j], 0, 0, 0);
    }
    __syncthreads();
  }
#pragma unroll
  for (int i = 0; i < 4; ++i) {
#pragma unroll
    for (int j = 0; j < 4; ++j) {
      f32x4 a4 = acc[i][j];
      int grow = row0 + wr * 64 + i * 16;
      int gcol = col0 + wc * 64 + j * 16;
      int t = gcol >> 5;
      int v0 = grow / K_N;
      int b = (v0 + 1) * K_N;
      int rbase = grow + ((lane >> 4) << 2);
      float s0 = 0.f, s1 = 0.f;
#pragma unroll
      for (int rg = 0; rg < 4; ++rg) {
        float x = a4[rg];
        float x2 = x * x;
        if (rbase + rg < b) s0 += x2; else s1 += x2;
      }
#pragma unroll
      for (int off = 32; off > 0; off >>= 1) {
        s0 += __shfl_xor(s0, off, 64);
        s1 += __shfl_xor(s1, off, 64);
      }
      if (lane == 0) {
        atomicAdd(out + v0 * T_N + t, s0);
        if (b < grow + 16) atomicAdd(out + (v0 + 1) * T_N + t, s1);
      }
    }
  }
}

extern "C" void kernel_launch(void* const* d_in, const int* in_sizes, int n_in,
                              void* d_out, int out_size, void* d_ws, size_t ws_size,
                              hipStream_t stream) {
  const float* imgs = (const float*)d_in[0];
  const float* caps = (const float*)d_in[1];
  float* out = (float*)d_out;

  hipMemsetAsync(d_out, 0, (size_t)V_N * T_N * sizeof(float), stream);

  const size_t need = (size_t)(MROWS + NROWS) * D_N;   // ~17.8 MB (fp8)

  if (ws_size >= need) {
    unsigned char* a8 = (unsigned char*)d_ws;
    unsigned char* b8 = a8 + (size_t)MROWS * D_N;
    cvt8<<<2048, 256, 0, stream>>>(imgs, caps, a8, b8);
    gemm2<<<NWG, 512, 0, stream>>>(a8, b8, out);
  } else {
    const int nwg = (MROWS / 128) * (NROWS / 128);
    gemm_fb<<<nwg, 256, 0, stream>>>(imgs, caps, out);
  }
}